// Round 12
// baseline (211.924 us; speedup 1.0000x reference)
//
#include <hip/hip_runtime.h>
#include <hip/hip_bf16.h>
#include <math.h>

#define NHh   8
#define EMB   256
#define HDd   32
#define NVv   6
#define SLENs 5440
#define QQ    1600
#define A_ATTN 3072   // NH*NV*NL*NP*NZ
#define A_OFF  6144

typedef _Float16 half8 __attribute__((ext_vector_type(8)));
typedef __attribute__((ext_vector_type(4))) float f32x4;

__device__ __forceinline__ unsigned short f2bf(float f) {
  __hip_bfloat16 h = __float2bfloat16(f);
  return *(unsigned short*)&h;
}
__device__ __forceinline__ unsigned short f2h(float f) {
  _Float16 h = (_Float16)f;
  return __builtin_bit_cast(unsigned short, h);
}
__device__ __forceinline__ float h2f(unsigned short u) {
  return (float)__builtin_bit_cast(_Float16, u);
}

// async global->LDS DMA, 16B per lane. LDS dest semantics: wave-uniform base
// + lane*16 (m104/m108) — caller must pass lane-ordered contiguous LDS addrs.
__device__ __forceinline__ void dma16(const unsigned short* g, unsigned short* l) {
  __builtin_amdgcn_global_load_lds(
      (const __attribute__((address_space(1))) unsigned int*)g,
      (__attribute__((address_space(3))) unsigned int*)l, 16, 0, 0);
}

// ---------------------------------------------------------------------------
// One-shot fp32 -> fp16 conversion of all GEMM operands.
// Woff/Wattn land contiguous in Wq16 (Wattn at element 1,572,864).
// ---------------------------------------------------------------------------
__global__ __launch_bounds__(256) void split_h_kernel(
    const float* __restrict__ q, const float* __restrict__ value,
    const float* __restrict__ Woff, const float* __restrict__ Wattn,
    const float* __restrict__ Wv, const float* __restrict__ Wout,
    unsigned short* __restrict__ q16, unsigned short* __restrict__ v16,
    unsigned short* __restrict__ Wq16, unsigned short* __restrict__ Wv16,
    unsigned short* __restrict__ Wout16) {
  int i4 = blockIdx.x * 256 + threadIdx.x;   // < 2,813,952 float4-chunks
  const float* src; unsigned short* dst; int sloc; int dloc;
  if      (i4 < 102400)  { src = q;     dst = q16;    sloc = i4;           dloc = sloc; }
  else if (i4 < 2191360) { src = value; dst = v16;    sloc = i4 - 102400;  dloc = sloc; }
  else if (i4 < 2584576) { src = Woff;  dst = Wq16;   sloc = i4 - 2191360; dloc = sloc; }
  else if (i4 < 2781184) { src = Wattn; dst = Wq16;   sloc = i4 - 2584576; dloc = sloc + 393216; }
  else if (i4 < 2797568) { src = Wv;    dst = Wv16;   sloc = i4 - 2781184; dloc = sloc; }
  else                   { src = Wout;  dst = Wout16; sloc = i4 - 2797568; dloc = sloc; }
  float4 x = ((const float4*)src)[sloc];
  ushort4 hh;
  hh.x = f2h(x.x); hh.y = f2h(x.y); hh.z = f2h(x.z); hh.w = f2h(x.w);
  ((ushort4*)dst)[dloc] = hh;
}

// ---------------------------------------------------------------------------
// Merged fp16 MFMA GEMM, round-12: DOUBLE-BUFFERED K-loop.
//   blocks [0, 936):    offs/attn GEMM  (M=1600, N=9216, tanh/bias epilogue)
//   blocks [936, 1446): val GEMM        (M=32640, N=256, bf16 permuted store)
// Pipelining: one barrier per iter; prefetch tile k+1 into buf^1 right after
// the barrier that publishes tile k, compute on tile k — the vmcnt(0) drain
// at the next barrier finds the prefetch ~compute-phase cycles along
// (round-11 lesson: 2-barrier full-drain loop was latency-serialized at
// ~130 TF). LDS 32 KB -> 5 blocks/CU. WAR on buf^1 safe: its readers passed
// the barrier (compiler emits lgkmcnt(0) before s_barrier).
// ---------------------------------------------------------------------------
__global__ __launch_bounds__(256) void gemm23_kernel(
    const unsigned short* __restrict__ q16, const unsigned short* __restrict__ Wq16,
    const unsigned short* __restrict__ v16, const unsigned short* __restrict__ Wv16,
    const float* __restrict__ boff, const float* __restrict__ battn,
    unsigned short* __restrict__ offs16, unsigned short* __restrict__ attn16,
    unsigned short* __restrict__ val_t) {
  __shared__ unsigned short LAh[2][128 * 32], LBh[2][128 * 32];

  const int bid = blockIdx.x;
  const unsigned short *A, *B;
  int M, bm, bn;
  bool isVal;
  if (bid < 936) {           // offs/attn: 72 n-tiles x 13 m-tiles
    A = q16;  B = Wq16;  M = QQ;
    bn = (bid % 72) * 128;  bm = (bid / 72) * 128;  isVal = false;
  } else {                   // val: 2 n-tiles x 255 m-tiles
    int b2 = bid - 936;
    A = v16;  B = Wv16;  M = NVv * SLENs;
    bn = (b2 & 1) * 128;  bm = (b2 >> 1) * 128;  isVal = true;
  }
  const int K = EMB;

  const int tid = threadIdx.x;
  const int lane = tid & 63, w = tid >> 6;
  const int wm = (w & 1) * 64, wn = (w >> 1) * 64;
  const int l16 = lane & 15, quad = lane >> 4;

  const int c0 = tid, c1 = tid + 256;
  const int r0 = c0 >> 2, s0 = (c0 & 3) * 8;
  const int r1 = c1 >> 2, s1 = (c1 & 3) * 8;
  const size_t a0 = (size_t)min(bm + r0, M - 1) * K + s0;
  const size_t a1 = (size_t)min(bm + r1, M - 1) * K + s1;
  const size_t b0o = (size_t)(bn + r0) * K + s0;
  const size_t b1o = (size_t)(bn + r1) * K + s1;
  const int l0 = c0 * 8, l1 = c1 * 8;

  f32x4 acc[4][4] = {};

  // prologue: stage tile 0 into buf 0
  dma16(&A[a0], &LAh[0][l0]);
  dma16(&A[a1], &LAh[0][l1]);
  dma16(&B[b0o], &LBh[0][l0]);
  dma16(&B[b1o], &LBh[0][l1]);

  for (int k0 = 0; k0 < K; k0 += 32) {
    const int buf = (k0 >> 5) & 1;
    __syncthreads();                 // vmcnt(0) drain: tile k0 in buf ready
    if (k0 + 32 < K) {               // prefetch tile k0+32 into buf^1
      const int nb = buf ^ 1;
      dma16(&A[a0 + k0 + 32], &LAh[nb][l0]);
      dma16(&A[a1 + k0 + 32], &LAh[nb][l1]);
      dma16(&B[b0o + k0 + 32], &LBh[nb][l0]);
      dma16(&B[b1o + k0 + 32], &LBh[nb][l1]);
    }

    half8 fa[4], fb[4];
#pragma unroll
    for (int i = 0; i < 4; ++i) {
      int ar = (wm + i * 16 + l16) * 32 + quad * 8;
      int br = (wn + i * 16 + l16) * 32 + quad * 8;
      fa[i] = *(const half8*)&LAh[buf][ar];
      fb[i] = *(const half8*)&LBh[buf][br];
    }
#pragma unroll
    for (int i = 0; i < 4; ++i)
#pragma unroll
      for (int j = 0; j < 4; ++j)
        acc[i][j] = __builtin_amdgcn_mfma_f32_16x16x32_f16(fa[i], fb[j], acc[i][j], 0, 0, 0);
  }

  // epilogue: C/D layout col(n)=lane&15, row(m)=quad*4+reg  [m89-verified]
#pragma unroll
  for (int j = 0; j < 4; ++j) {
    int n = bn + wn + j * 16 + l16;
    float bv = 0.f;
    bool dotanh = false;
    if (!isVal) {
      if (n < A_OFF) { bv = boff[n]; dotanh = true; }
      else bv = battn[n - A_OFF];
    }
#pragma unroll
    for (int i = 0; i < 4; ++i) {
      int mbase = bm + wm + i * 16 + quad * 4;
#pragma unroll
      for (int reg = 0; reg < 4; ++reg) {
        int m = mbase + reg;
        if (m >= M) continue;
        float c = acc[i][j][reg] + bv;
        if (isVal) {   // bf16 permuted store: m=(v*SLEN+s), n=(h*32+d)
          int vv = m / SLENs;
          int s = m - vv * SLENs;
          int hh2 = n >> 5, dd = n & 31;
          val_t[((size_t)(vv * 8 + hh2) * SLENs + s) * 32 + dd] = f2bf(c);
        } else if (dotanh) {
          float t = __expf(2.f * c);
          c = 1.f - 2.f / (t + 1.f);
          offs16[(size_t)m * A_OFF + n] = f2h(c);
        } else {
          attn16[(size_t)m * A_ATTN + (n - A_OFF)] = f2h(c);
        }
      }
    }
  }
}

// ---------------------------------------------------------------------------
// fp16 MFMA GEMM, final out = out_pre @ Wout.T (f32 store), double-buffered.
// ---------------------------------------------------------------------------
__global__ __launch_bounds__(256) void gemmh0_kernel(
    const unsigned short* __restrict__ Ah, const unsigned short* __restrict__ Bh,
    float* __restrict__ C, int M, int N, int K) {
  __shared__ unsigned short LAh[2][128 * 32], LBh[2][128 * 32];

  const int tid = threadIdx.x;
  const int bm = blockIdx.y * 128, bn = blockIdx.x * 128;
  const int lane = tid & 63, w = tid >> 6;
  const int wm = (w & 1) * 64, wn = (w >> 1) * 64;
  const int l16 = lane & 15, quad = lane >> 4;

  const int c0 = tid, c1 = tid + 256;
  const int r0 = c0 >> 2, s0 = (c0 & 3) * 8;
  const int r1 = c1 >> 2, s1 = (c1 & 3) * 8;
  const size_t a0 = (size_t)min(bm + r0, M - 1) * K + s0;
  const size_t a1 = (size_t)min(bm + r1, M - 1) * K + s1;
  const size_t b0o = (size_t)(bn + r0) * K + s0;
  const size_t b1o = (size_t)(bn + r1) * K + s1;
  const int l0 = c0 * 8, l1 = c1 * 8;

  f32x4 acc[4][4] = {};

  dma16(&Ah[a0], &LAh[0][l0]);
  dma16(&Ah[a1], &LAh[0][l1]);
  dma16(&Bh[b0o], &LBh[0][l0]);
  dma16(&Bh[b1o], &LBh[0][l1]);

  for (int k0 = 0; k0 < K; k0 += 32) {
    const int buf = (k0 >> 5) & 1;
    __syncthreads();
    if (k0 + 32 < K) {
      const int nb = buf ^ 1;
      dma16(&Ah[a0 + k0 + 32], &LAh[nb][l0]);
      dma16(&Ah[a1 + k0 + 32], &LAh[nb][l1]);
      dma16(&Bh[b0o + k0 + 32], &LBh[nb][l0]);
      dma16(&Bh[b1o + k0 + 32], &LBh[nb][l1]);
    }

    half8 fa[4], fb[4];
#pragma unroll
    for (int i = 0; i < 4; ++i) {
      int ar = (wm + i * 16 + l16) * 32 + quad * 8;
      int br = (wn + i * 16 + l16) * 32 + quad * 8;
      fa[i] = *(const half8*)&LAh[buf][ar];
      fb[i] = *(const half8*)&LBh[buf][br];
    }
#pragma unroll
    for (int i = 0; i < 4; ++i)
#pragma unroll
      for (int j = 0; j < 4; ++j)
        acc[i][j] = __builtin_amdgcn_mfma_f32_16x16x32_f16(fa[i], fb[j], acc[i][j], 0, 0, 0);
  }

#pragma unroll
  for (int j = 0; j < 4; ++j) {
    int n = bn + wn + j * 16 + l16;
#pragma unroll
    for (int i = 0; i < 4; ++i) {
      int mbase = bm + wm + i * 16 + quad * 4;
#pragma unroll
      for (int reg = 0; reg < 4; ++reg) {
        int m = mbase + reg;
        if (m >= M) continue;
        C[(size_t)m * N + n] = acc[i][j][reg];
      }
    }
  }
}

// ---------------------------------------------------------------------------
// Fused softmax + record build + sampling (UNCHANGED from round 11).
// Wave = one (q,h). Phase 1: softmax + per-record 4 corner byte-offsets
// (int4) + 4 corner bf16 weights into wave-private LDS (no barrier).
// Phase 2: v3c hot loop — outer loops unroll-limited (round-5 spill lesson),
// lane r's records spaced 4 apart (round-6 lesson), val_t bf16.
// ---------------------------------------------------------------------------
__global__ __launch_bounds__(256) void sample_kernel(
    const float* __restrict__ ref, const unsigned short* __restrict__ offs16,
    const unsigned short* __restrict__ attn16,
    const unsigned short* __restrict__ val_t,
    unsigned short* __restrict__ op16) {
  __shared__ int4  Lco[4][384];   // per-record corner byte offsets {o00,o01,o10,o11}
  __shared__ uint2 Lrw[4][384];   // per-record corner weights bf16 {w00,w01,w10,w11}

  const int h   = blockIdx.x & 7;      // XCD L2 affinity: 6 slices ~2.1MB
  const int qt  = blockIdx.x >> 3;
  const int wid = threadIdx.x >> 6;
  const int lane = threadIdx.x & 63;
  const int q   = qt * 4 + wid;
  const int row = q * 8 + h;

  // ---- phase 1: softmax + records ----
  {
    const unsigned short* ap = attn16 + (size_t)row * 384;
    float vals[6];
    float mx = -1e30f;
#pragma unroll
    for (int i = 0; i < 6; ++i) { vals[i] = h2f(ap[lane + i * 64]); mx = fmaxf(mx, vals[i]); }
#pragma unroll
    for (int o = 32; o > 0; o >>= 1) mx = fmaxf(mx, __shfl_xor(mx, o, 64));
    float s = 0.f;
#pragma unroll
    for (int i = 0; i < 6; ++i) { vals[i] = __expf(vals[i] - mx); s += vals[i]; }
#pragma unroll
    for (int o = 32; o > 0; o >>= 1) s += __shfl_xor(s, o, 64);
    const float inv = 1.0f / s;

    const int l = (lane >> 4) & 3;
    const int z = lane & 3;
    const int Wl = 64 >> l;
    const int start = (l == 0) ? 0 : (l == 1 ? 4096 : (l == 2 ? 5120 : 5376));
    const int strideB = 4096 >> l;       // Wl * 64 bytes
    const float sc = 0.5f * (float)(Wl - 1);
    const unsigned int* op = (const unsigned int*)offs16 + (size_t)row * 384;
    const float* rq = ref + (size_t)q * (NVv * 4 * 4 * 2);

#pragma unroll 1
    for (int v = 0; v < 6; ++v) {
      int j = v * 64 + lane;
      float w = vals[v] * inv;
      unsigned int oxy = op[j];              // fp16 pair: lo=x, hi=y
      float ox = h2f((unsigned short)(oxy & 0xFFFF));
      float oy = h2f((unsigned short)(oxy >> 16));
      const float* rp = rq + ((v * 4 + l) * 4 + z) * 2;
      float rx = rp[0], ry = rp[1];
      float x = fminf(1.f, fmaxf(-1.f, rx + ox));
      float y = fminf(1.f, fmaxf(-1.f, ry + oy));
      float xp = (x + 1.f) * sc, yp = (y + 1.f) * sc;
      float x0f = floorf(xp), y0f = floorf(yp);
      int x0 = (int)x0f, y0 = (int)y0f;      // xp,yp >= 0 -> trunc == floor
      float wx = xp - x0f, wy = yp - y0f;
      int b0 = (start + y0 * Wl + x0) << 6;
      int dx = (x0 + 1 < Wl) ? 64 : 0;
      int dy = (y0 + 1 < Wl) ? strideB : 0;
      float wxw = wx * w, wmx = w - wxw;
      float w01 = wxw * (1.f - wy), w11 = wxw * wy;
      float w00 = wmx * (1.f - wy), w10 = wmx * wy;
      Lco[wid][j] = make_int4(b0, b0 + dx, b0 + dy, b0 + dx + dy);
      Lrw[wid][j] = make_uint2(((unsigned)f2bf(w01) << 16) | f2bf(w00),
                               ((unsigned)f2bf(w11) << 16) | f2bf(w10));
    }
  }
  // no __syncthreads: each wave consumes only its own Lco/Lrw slice

  // ---- phase 2: sampling (bf16 val_t) ----
  const int cb  = (lane >> 2) & 3;          // corner index = cx + 2*cy
  const int e16 = (lane & 3) << 4;          // channel-oct byte offset
  const int r   = lane >> 4;

  const int* LcoW = (const int*)&Lco[wid][0];
  const unsigned short* LrwW = (const unsigned short*)&Lrw[wid][0];

  float acc[8] = {};

#pragma unroll 1
  for (int v = 0; v < 6; ++v) {
    const char* sb = (const char*)val_t + (size_t)(v * 8 + h) * (SLENs * 64);
    const int rbase = v * 64 + r;
#pragma unroll 4
    for (int t = 0; t < 16; ++t) {
      int ri = rbase + t * 4;               // lane r's records, spaced 4
      int off = LcoW[ri * 4 + cb];
      float wl_ = __uint_as_float((unsigned int)LrwW[ri * 4 + cb] << 16);
      uint4 u = *(const uint4*)(sb + (off + e16));
      acc[0] = fmaf(wl_, __uint_as_float(u.x << 16),          acc[0]);
      acc[1] = fmaf(wl_, __uint_as_float(u.x & 0xFFFF0000u),  acc[1]);
      acc[2] = fmaf(wl_, __uint_as_float(u.y << 16),          acc[2]);
      acc[3] = fmaf(wl_, __uint_as_float(u.y & 0xFFFF0000u),  acc[3]);
      acc[4] = fmaf(wl_, __uint_as_float(u.z << 16),          acc[4]);
      acc[5] = fmaf(wl_, __uint_as_float(u.z & 0xFFFF0000u),  acc[5]);
      acc[6] = fmaf(wl_, __uint_as_float(u.w << 16),          acc[6]);
      acc[7] = fmaf(wl_, __uint_as_float(u.w & 0xFFFF0000u),  acc[7]);
    }
  }

#pragma unroll
  for (int m = 4; m <= 32; m <<= 1)
#pragma unroll
    for (int j = 0; j < 8; ++j) acc[j] += __shfl_xor(acc[j], m, 64);

  if (lane < 4) {
    int off = q * EMB + h * 32 + lane * 8;
    ushort4 h0, h1;
    h0.x = f2h(acc[0]); h0.y = f2h(acc[1]); h0.z = f2h(acc[2]); h0.w = f2h(acc[3]);
    h1.x = f2h(acc[4]); h1.y = f2h(acc[5]); h1.z = f2h(acc[6]); h1.w = f2h(acc[7]);
    *(ushort4*)&op16[off] = h0;  *(ushort4*)&op16[off + 4] = h1;
  }
}

// ---------------------------------------------------------------------------
extern "C" void kernel_launch(void* const* d_in, const int* in_sizes, int n_in,
                              void* d_out, int out_size, void* d_ws, size_t ws_size,
                              hipStream_t stream) {
  const float* queries    = (const float*)d_in[0];
  const float* ref_points = (const float*)d_in[1];
  const float* value      = (const float*)d_in[2];
  const float* Wv    = (const float*)d_in[4];
  const float* Woff  = (const float*)d_in[5];
  const float* boff  = (const float*)d_in[6];
  const float* Wattn = (const float*)d_in[7];
  const float* battn = (const float*)d_in[8];
  const float* Wout  = (const float*)d_in[9];
  float* out = (float*)d_out;

  // ws layout, byte offsets — total 69.5 MB (well under proven 155 MB).
  char* W = (char*)d_ws;
  unsigned short* offs16 = (unsigned short*)(W + 0);         // 19,660,800
  unsigned short* attn16 = (unsigned short*)(W + 19660800);  //  9,830,400
  unsigned short* val_t  = (unsigned short*)(W + 29491200);  // 16,711,680 (bf16)
  unsigned short* q16    = (unsigned short*)(W + 46202880);  //    819,200
  unsigned short* v16    = (unsigned short*)(W + 47022080);  // 16,711,680
  unsigned short* Wq16   = (unsigned short*)(W + 63733760);  //  4,718,592 (Woff||Wattn)
  unsigned short* Wv16   = (unsigned short*)(W + 68452352);  //    131,072
  unsigned short* Wout16 = (unsigned short*)(W + 68583424);  //    131,072
  unsigned short* op16   = (unsigned short*)(W + 68714496);  //    819,200

  dim3 blk(256);

  // 1. convert all GEMM operands to fp16 (single-pass)
  split_h_kernel<<<10992, blk, 0, stream>>>(
      queries, value, Woff, Wattn, Wv, Wout, q16, v16, Wq16, Wv16, Wout16);
  // 2. merged offs/attn GEMM (936 blocks) + val GEMM (510 blocks), dbuf
  gemm23_kernel<<<1446, blk, 0, stream>>>(
      q16, Wq16, v16, Wv16, boff, battn, offs16, attn16, val_t);
  // 3. fused softmax + record build + sampling -> out_pre fp16
  sample_kernel<<<QQ * NHh / 4, blk, 0, stream>>>(
      ref_points, offs16, attn16, val_t, op16);
  // 4. out = out_pre @ Wout.T (fp16 in, fp32 out), dbuf
  gemmh0_kernel<<<dim3(EMB / 128, (QQ + 127) / 128), blk, 0, stream>>>(
      op16, Wout16, out, QQ, EMB, EMB);
}